// Round 1
// baseline (231.517 us; speedup 1.0000x reference)
//
#include <hip/hip_runtime.h>

// OuterProductMean, factored:
//   S[l,t]   = gamma[t] * sum_n (m[n,l,t]-mu[n,l])*rstd[n,l] + N*beta[t]
//   a2[l,c]  = (S[l,:] @ Wi)/N + bi   (b2 likewise with Wj, bj)
//   T[j,c,z] = sum_d b2[j,d] * Wo[(c*16+d)*128 + z]
//   out[i,j,z] = sum_c a2[i,c]*T[j,c,z] + bo[z]
// FLOPs drop from 17.2G (naive bic,bjd,cdz) to ~1.1G; memory floor is the
// 134 MB output write + 67 MB read of m (~32 us at 6.3 TB/s).

#define LN_EPS 1e-5f

constexpr int N_SEQ = 128;
constexpr int L_DIM = 512;
constexpr int CM    = 256;   // c_m
constexpr int CH    = 16;    // c
constexpr int CZ    = 128;   // c_z
constexpr int NPART = 4;     // N-partitions in kernel 1

// ---------------- Kernel 1: LN stats + sum over its N-slice ----------------
// grid (L, NPART), block 256 (4 waves). Wave w handles rows n = p*32+w*8+r.
__global__ __launch_bounds__(256) void k1_ln_rowsum(
    const float* __restrict__ m, float* __restrict__ partial)
{
  const int l    = blockIdx.x;
  const int p    = blockIdx.y;
  const int t    = threadIdx.x;
  const int wave = t >> 6;
  const int lane = t & 63;

  float s0 = 0.f, s1 = 0.f, s2 = 0.f, s3 = 0.f;
  for (int r = 0; r < 8; ++r) {
    const int n = p * 32 + wave * 8 + r;
    const float4 v = *((const float4*)(m + ((size_t)n * L_DIM + l) * CM) + lane);
    float sum = v.x + v.y + v.z + v.w;
    float sq  = v.x * v.x + v.y * v.y + v.z * v.z + v.w * v.w;
#pragma unroll
    for (int off = 1; off < 64; off <<= 1) {
      sum += __shfl_xor(sum, off, 64);
      sq  += __shfl_xor(sq,  off, 64);
    }
    const float mu   = sum * (1.0f / CM);
    const float var  = sq * (1.0f / CM) - mu * mu;
    const float rstd = rsqrtf(var + LN_EPS);
    s0 += (v.x - mu) * rstd;
    s1 += (v.y - mu) * rstd;
    s2 += (v.z - mu) * rstd;
    s3 += (v.w - mu) * rstd;
  }

  __shared__ float sacc[4][CM];
  *((float4*)&sacc[wave][4 * lane]) = make_float4(s0, s1, s2, s3);
  __syncthreads();
  const float s = sacc[0][t] + sacc[1][t] + sacc[2][t] + sacc[3][t];
  partial[((size_t)p * L_DIM + l) * CM + t] = s;
}

// ---------------- Kernel 2: per-l projection + T build ----------------
// grid (L), block 256.
__global__ __launch_bounds__(256) void k2_proj(
    const float* __restrict__ partial,
    const float* __restrict__ gamma, const float* __restrict__ beta,
    const float* __restrict__ Wi, const float* __restrict__ bi,
    const float* __restrict__ Wj, const float* __restrict__ bj,
    const float* __restrict__ Wo,
    float* __restrict__ a2, float* __restrict__ T)
{
  const int l = blockIdx.x;
  const int t = threadIdx.x;

  __shared__ float s_lds[CM];
  __shared__ float pacc[32][9];   // +1 pad breaks stride-8 bank aliasing
  __shared__ float ab[32];        // [0..15]=a2(l,:), [16..31]=b2(l,:)

  float s = 0.f;
  for (int p = 0; p < NPART; ++p)
    s += partial[((size_t)p * L_DIM + l) * CM + t];
  s = gamma[t] * s + (float)N_SEQ * beta[t];
  s_lds[t] = s;
  __syncthreads();

  // 32 channels (16 a + 16 b), 8 threads each over 32 elements
  const int ch  = t >> 3;
  const int sub = t & 7;
  const int c   = ch & 15;
  const float* __restrict__ W = (ch < CH) ? Wi : Wj;
  float acc = 0.f;
  for (int k = 0; k < 32; ++k) {
    const int e = sub * 32 + k;
    acc += s_lds[e] * W[e * CH + c];
  }
  pacc[ch][sub] = acc;
  __syncthreads();

  if (t < 32) {
    float a = 0.f;
    for (int q = 0; q < 8; ++q) a += pacc[t][q];
    a = a * (1.0f / N_SEQ) + ((t < CH) ? bi[t] : bj[t - CH]);
    ab[t] = a;
    if (t < CH) a2[l * CH + t] = a;
  }
  __syncthreads();

  // T[l][cc][z] = sum_d b2[d] * Wo[(cc*16+d)*CZ + z]
  const int z   = t & (CZ - 1);
  const int chi = t >> 7;  // 0..1
  for (int q = 0; q < 8; ++q) {
    const int cc = chi * 8 + q;
    float accT = 0.f;
#pragma unroll
    for (int d = 0; d < CH; ++d)
      accT += ab[CH + d] * Wo[(cc * CH + d) * CZ + z];
    T[((size_t)l * CH + cc) * CZ + z] = accT;
  }
}

// ---------------- Kernel 3: out[i,j,z] = sum_c a2[i,c]*T[j,c,z] + bo[z] ----
// grid (L=j, 4 = i-chunk), block 256. Thread: z-quad = t&31, i_base = t>>5.
__global__ __launch_bounds__(256) void k3_out(
    const float* __restrict__ a2, const float* __restrict__ T,
    const float* __restrict__ bo, float* __restrict__ out)
{
  const int j  = blockIdx.x;
  const int ic = blockIdx.y;
  const int t  = threadIdx.x;

  __shared__ float Ts[CH * CZ];   // 2048 floats, T[j] tile
  __shared__ float As[128 * CH];  // 2048 floats, a2 chunk

  {
    const float4* Tg = (const float4*)(T + (size_t)j * CH * CZ);
    float4* Tl = (float4*)Ts;
    Tl[t]       = Tg[t];
    Tl[t + 256] = Tg[t + 256];
    const float4* Ag = (const float4*)(a2 + (size_t)ic * 128 * CH);
    float4* Al = (float4*)As;
    Al[t]       = Ag[t];
    Al[t + 256] = Ag[t + 256];
  }
  __syncthreads();

  const int z4    = t & 31;  // which float4 of the 128 z's
  const int ibase = t >> 5;  // 0..7

  float4 Treg[CH];
#pragma unroll
  for (int c = 0; c < CH; ++c)
    Treg[c] = ((const float4*)(Ts + c * CZ))[z4];
  const float4 bov = ((const float4*)bo)[z4];

#define FMA4(av, tv) { acc.x += (av)*(tv).x; acc.y += (av)*(tv).y; \
                       acc.z += (av)*(tv).z; acc.w += (av)*(tv).w; }
  for (int q = 0; q < 16; ++q) {
    const int il = ibase + 8 * q;
    const float4* arow = (const float4*)(As + il * CH);
    const float4 a0 = arow[0], a1 = arow[1], a2v = arow[2], a3 = arow[3];
    float4 acc = bov;
    FMA4(a0.x, Treg[0]);  FMA4(a0.y, Treg[1]);  FMA4(a0.z, Treg[2]);  FMA4(a0.w, Treg[3]);
    FMA4(a1.x, Treg[4]);  FMA4(a1.y, Treg[5]);  FMA4(a1.z, Treg[6]);  FMA4(a1.w, Treg[7]);
    FMA4(a2v.x, Treg[8]); FMA4(a2v.y, Treg[9]); FMA4(a2v.z, Treg[10]); FMA4(a2v.w, Treg[11]);
    FMA4(a3.x, Treg[12]); FMA4(a3.y, Treg[13]); FMA4(a3.z, Treg[14]); FMA4(a3.w, Treg[15]);
    const int i = ic * 128 + il;
    ((float4*)(out + ((size_t)i * L_DIM + j) * CZ))[z4] = acc;
  }
#undef FMA4
}

extern "C" void kernel_launch(void* const* d_in, const int* in_sizes, int n_in,
                              void* d_out, int out_size, void* d_ws, size_t ws_size,
                              hipStream_t stream) {
  const float* m     = (const float*)d_in[0];
  const float* gamma = (const float*)d_in[1];
  const float* beta  = (const float*)d_in[2];
  const float* Wi    = (const float*)d_in[3];
  const float* bi    = (const float*)d_in[4];
  const float* Wj    = (const float*)d_in[5];
  const float* bj    = (const float*)d_in[6];
  const float* Wo    = (const float*)d_in[7];
  const float* bo    = (const float*)d_in[8];
  float* out = (float*)d_out;

  char* ws = (char*)d_ws;
  float* partial = (float*)ws;                                   // 2 MiB
  float* a2      = (float*)(ws + (size_t)NPART * L_DIM * CM * 4);      // 32 KiB
  float* T       = (float*)(ws + (size_t)NPART * L_DIM * CM * 4
                               + (size_t)L_DIM * CH * 4);              // 4 MiB

  k1_ln_rowsum<<<dim3(L_DIM, NPART), 256, 0, stream>>>(m, partial);
  k2_proj<<<dim3(L_DIM), 256, 0, stream>>>(partial, gamma, beta,
                                           Wi, bi, Wj, bj, Wo, a2, T);
  k3_out<<<dim3(L_DIM, NPART), 256, 0, stream>>>(a2, T, bo, out);
}

// Round 3
// 214.444 us; speedup vs baseline: 1.0796x; 1.0796x over previous
//
#include <hip/hip_runtime.h>

// OuterProductMean, factored:
//   S[l,t]   = gamma[t] * sum_n (m[n,l,t]-mu[n,l])*rstd[n,l] + N*beta[t]
//   a2[l,c]  = (S[l,:] @ Wi)/N + bi   (b2 likewise with Wj, bj)
//   T[j,c,z] = sum_d b2[j,d] * Wo[(c*16+d)*128 + z]
//   out[i,j,z] = sum_c a2[i,c]*T[j,c,z] + bo[z]
// Memory floor: 134 MB out write + 67 MB m read ~= 32 us at 6.3 TB/s.

#define LN_EPS 1e-5f

constexpr int N_SEQ = 128;
constexpr int L_DIM = 512;
constexpr int CM    = 256;   // c_m
constexpr int CH    = 16;    // c
constexpr int CZ    = 128;   // c_z
constexpr int NPART = 4;     // N-partitions in kernel 1

typedef float floatx4 __attribute__((ext_vector_type(4)));

// ---------------- Kernel 1: LN stats + sum over its N-slice ----------------
// grid (L, NPART), block 256 (4 waves). Wave w handles rows n = p*32+w*8+r.
// All 8 row-loads issued up-front so the 6-stage shuffle chains overlap them.
__global__ __launch_bounds__(256) void k1_ln_rowsum(
    const float* __restrict__ m, float* __restrict__ partial)
{
  const int l    = blockIdx.x;
  const int p    = blockIdx.y;
  const int t    = threadIdx.x;
  const int wave = t >> 6;
  const int lane = t & 63;

  float4 v[8];
#pragma unroll
  for (int r = 0; r < 8; ++r) {
    const int n = p * 32 + wave * 8 + r;
    v[r] = *((const float4*)(m + ((size_t)n * L_DIM + l) * CM) + lane);
  }

  float s0 = 0.f, s1 = 0.f, s2 = 0.f, s3 = 0.f;
#pragma unroll
  for (int r = 0; r < 8; ++r) {
    float sum = v[r].x + v[r].y + v[r].z + v[r].w;
    float sq  = v[r].x * v[r].x + v[r].y * v[r].y + v[r].z * v[r].z + v[r].w * v[r].w;
#pragma unroll
    for (int off = 1; off < 64; off <<= 1) {
      sum += __shfl_xor(sum, off, 64);
      sq  += __shfl_xor(sq,  off, 64);
    }
    const float mu   = sum * (1.0f / CM);
    const float var  = sq * (1.0f / CM) - mu * mu;
    const float rstd = rsqrtf(var + LN_EPS);
    s0 += (v[r].x - mu) * rstd;
    s1 += (v[r].y - mu) * rstd;
    s2 += (v[r].z - mu) * rstd;
    s3 += (v[r].w - mu) * rstd;
  }

  __shared__ float sacc[4][CM];
  *((float4*)&sacc[wave][4 * lane]) = make_float4(s0, s1, s2, s3);
  __syncthreads();
  const float s = sacc[0][t] + sacc[1][t] + sacc[2][t] + sacc[3][t];
  partial[((size_t)p * L_DIM + l) * CM + t] = s;
}

// ---------------- Kernel 2: per-l projection + T build ----------------
// grid (L), block 256.
__global__ __launch_bounds__(256) void k2_proj(
    const float* __restrict__ partial,
    const float* __restrict__ gamma, const float* __restrict__ beta,
    const float* __restrict__ Wi, const float* __restrict__ bi,
    const float* __restrict__ Wj, const float* __restrict__ bj,
    const float* __restrict__ Wo,
    float* __restrict__ a2, float* __restrict__ T)
{
  const int l = blockIdx.x;
  const int t = threadIdx.x;

  __shared__ float s_lds[CM];
  __shared__ float pacc[32][9];   // +1 pad breaks stride-8 bank aliasing
  __shared__ float ab[32];        // [0..15]=a2(l,:), [16..31]=b2(l,:)

  float s = 0.f;
  for (int p = 0; p < NPART; ++p)
    s += partial[((size_t)p * L_DIM + l) * CM + t];
  s = gamma[t] * s + (float)N_SEQ * beta[t];
  s_lds[t] = s;
  __syncthreads();

  // 32 channels (16 a + 16 b), 8 threads each over 32 elements
  const int ch  = t >> 3;
  const int sub = t & 7;
  const int c   = ch & 15;
  const float* __restrict__ W = (ch < CH) ? Wi : Wj;
  float acc = 0.f;
  for (int k = 0; k < 32; ++k) {
    const int e = sub * 32 + k;
    acc += s_lds[e] * W[e * CH + c];
  }
  pacc[ch][sub] = acc;
  __syncthreads();

  if (t < 32) {
    float a = 0.f;
    for (int q = 0; q < 8; ++q) a += pacc[t][q];
    a = a * (1.0f / N_SEQ) + ((t < CH) ? bi[t] : bj[t - CH]);
    ab[t] = a;
    if (t < CH) a2[l * CH + t] = a;
  }
  __syncthreads();

  // T[l][cc][z] = sum_d b2[d] * Wo[(cc*16+d)*CZ + z]
  const int z   = t & (CZ - 1);
  const int chi = t >> 7;  // 0..1
  for (int q = 0; q < 8; ++q) {
    const int cc = chi * 8 + q;
    float accT = 0.f;
#pragma unroll
    for (int d = 0; d < CH; ++d)
      accT += ab[CH + d] * Wo[(cc * CH + d) * CZ + z];
    T[((size_t)l * CH + cc) * CZ + z] = accT;
  }
}

// ---------------- Kernel 3: out[i,j,z] = sum_c a2[i,c]*T[j,c,z] + bo[z] ----
// grid (64 j-chunks, 16 i-chunks), block 256, no LDS, no barriers.
// Thread (z4 = t&31, js = t>>5) pins T[j0+js][*][z4] in 64 VGPRs, loops 32 i.
// a2[i,:] is block-uniform -> scalar loads. Wave stores 1 KB contiguous.
__global__ __launch_bounds__(256) void k3_out(
    const float* __restrict__ a2, const float* __restrict__ T,
    const float* __restrict__ bo, float* __restrict__ out)
{
  const int t  = threadIdx.x;
  const int z4 = t & 31;   // which float4 of the 128 z's
  const int j  = blockIdx.x * 8 + (t >> 5);
  const int i0 = blockIdx.y * 32;

  float4 Treg[CH];
  {
    const float4* Tg = (const float4*)T + (size_t)j * (CH * 32) + z4;
#pragma unroll
    for (int c = 0; c < CH; ++c)
      Treg[c] = Tg[c * 32];
  }
  const float4 bov = ((const float4*)bo)[z4];

#define FMA4(av, tv) { acc.x += (av)*(tv).x; acc.y += (av)*(tv).y; \
                       acc.z += (av)*(tv).z; acc.w += (av)*(tv).w; }
  for (int ii = 0; ii < 32; ++ii) {
    const int i = i0 + ii;
    const float4* ar4 = (const float4*)(a2 + (size_t)i * CH);  // uniform -> s_load
    const float4 a0 = ar4[0], a1 = ar4[1], a2v = ar4[2], a3 = ar4[3];
    float4 acc = bov;
    FMA4(a0.x, Treg[0]);  FMA4(a0.y, Treg[1]);  FMA4(a0.z, Treg[2]);  FMA4(a0.w, Treg[3]);
    FMA4(a1.x, Treg[4]);  FMA4(a1.y, Treg[5]);  FMA4(a1.z, Treg[6]);  FMA4(a1.w, Treg[7]);
    FMA4(a2v.x, Treg[8]); FMA4(a2v.y, Treg[9]); FMA4(a2v.z, Treg[10]); FMA4(a2v.w, Treg[11]);
    FMA4(a3.x, Treg[12]); FMA4(a3.y, Treg[13]); FMA4(a3.z, Treg[14]); FMA4(a3.w, Treg[15]);
    floatx4* dst = (floatx4*)(out + ((size_t)i * L_DIM + j) * CZ) + z4;
    floatx4 accv = { acc.x, acc.y, acc.z, acc.w };
    __builtin_nontemporal_store(accv, dst);
  }
#undef FMA4
}

extern "C" void kernel_launch(void* const* d_in, const int* in_sizes, int n_in,
                              void* d_out, int out_size, void* d_ws, size_t ws_size,
                              hipStream_t stream) {
  const float* m     = (const float*)d_in[0];
  const float* gamma = (const float*)d_in[1];
  const float* beta  = (const float*)d_in[2];
  const float* Wi    = (const float*)d_in[3];
  const float* bi    = (const float*)d_in[4];
  const float* Wj    = (const float*)d_in[5];
  const float* bj    = (const float*)d_in[6];
  const float* Wo    = (const float*)d_in[7];
  const float* bo    = (const float*)d_in[8];
  float* out = (float*)d_out;

  char* ws = (char*)d_ws;
  float* partial = (float*)ws;                                         // 2 MiB
  float* a2      = (float*)(ws + (size_t)NPART * L_DIM * CM * 4);      // 32 KiB
  float* T       = (float*)(ws + (size_t)NPART * L_DIM * CM * 4
                               + (size_t)L_DIM * CH * 4);              // 4 MiB

  k1_ln_rowsum<<<dim3(L_DIM, NPART), 256, 0, stream>>>(m, partial);
  k2_proj<<<dim3(L_DIM), 256, 0, stream>>>(partial, gamma, beta,
                                           Wi, bi, Wj, bj, Wo, a2, T);
  k3_out<<<dim3(64, 16), 256, 0, stream>>>(a2, T, bo, out);
}

// Round 4
// 210.461 us; speedup vs baseline: 1.1000x; 1.0189x over previous
//
#include <hip/hip_runtime.h>

// OuterProductMean, factored:
//   S[l,t]   = gamma[t] * sum_n (m[n,l,t]-mu[n,l])*rstd[n,l] + N*beta[t]
//   a2[l,c]  = (S[l,:] @ Wi)/N + bi   (b2 likewise with Wj, bj)
//   T[j,c,z] = sum_d b2[j,d] * Wo[(c*16+d)*128 + z]
//   out[i,j,z] = sum_c a2[i,c]*T[j,c,z] + bo[z]
// Memory floor: 134 MB out write + 67 MB m read ~= 32 us at 6.3 TB/s.
// kA: LN+rowsum+projection+T fused, one block per l (4 waves x 32 rows = N).
// kB: rank-16 expansion, T[j] pinned in 64 VGPRs, 64 i per block.

#define LN_EPS 1e-5f

constexpr int N_SEQ = 128;
constexpr int L_DIM = 512;
constexpr int CM    = 256;   // c_m
constexpr int CH    = 16;    // c
constexpr int CZ    = 128;   // c_z

typedef float floatx4 __attribute__((ext_vector_type(4)));

// ---------------- Kernel A: LN stats + N-sum + projections + T build -------
// grid (L), block 256 (4 waves). Wave w handles rows n = w*32 .. w*32+31.
__global__ __launch_bounds__(256) void kA_ln_proj(
    const float* __restrict__ m,
    const float* __restrict__ gamma, const float* __restrict__ beta,
    const float* __restrict__ Wi, const float* __restrict__ bi,
    const float* __restrict__ Wj, const float* __restrict__ bj,
    const float* __restrict__ Wo,
    float* __restrict__ a2, float* __restrict__ T)
{
  const int l    = blockIdx.x;
  const int t    = threadIdx.x;
  const int wave = t >> 6;
  const int lane = t & 63;

  float s0 = 0.f, s1 = 0.f, s2 = 0.f, s3 = 0.f;
  for (int rb = 0; rb < 4; ++rb) {
    float4 v[8];
#pragma unroll
    for (int r = 0; r < 8; ++r) {
      const int n = wave * 32 + rb * 8 + r;
      v[r] = *((const float4*)(m + ((size_t)n * L_DIM + l) * CM) + lane);
    }
#pragma unroll
    for (int r = 0; r < 8; ++r) {
      float sum = v[r].x + v[r].y + v[r].z + v[r].w;
      float sq  = v[r].x * v[r].x + v[r].y * v[r].y + v[r].z * v[r].z + v[r].w * v[r].w;
#pragma unroll
      for (int off = 1; off < 64; off <<= 1) {
        sum += __shfl_xor(sum, off, 64);
        sq  += __shfl_xor(sq,  off, 64);
      }
      const float mu   = sum * (1.0f / CM);
      const float var  = sq * (1.0f / CM) - mu * mu;
      const float rstd = rsqrtf(var + LN_EPS);
      s0 += (v[r].x - mu) * rstd;
      s1 += (v[r].y - mu) * rstd;
      s2 += (v[r].z - mu) * rstd;
      s3 += (v[r].w - mu) * rstd;
    }
  }

  __shared__ float sacc[4][CM];
  __shared__ float s_lds[CM];
  __shared__ float pacc[32][9];   // +1 pad breaks stride-8 bank aliasing
  __shared__ float ab[32];        // [0..15]=a2(l,:), [16..31]=b2(l,:)

  *((float4*)&sacc[wave][4 * lane]) = make_float4(s0, s1, s2, s3);
  __syncthreads();
  // channel t: total over N, then gamma/beta fold
  s_lds[t] = gamma[t] * (sacc[0][t] + sacc[1][t] + sacc[2][t] + sacc[3][t])
           + (float)N_SEQ * beta[t];
  __syncthreads();

  // 32 channels (16 a + 16 b), 8 threads each over 32 elements
  const int ch  = t >> 3;
  const int sub = t & 7;
  const int c   = ch & 15;
  const float* __restrict__ W = (ch < CH) ? Wi : Wj;
  float acc = 0.f;
  for (int k = 0; k < 32; ++k) {
    const int e = sub * 32 + k;
    acc += s_lds[e] * W[e * CH + c];
  }
  pacc[ch][sub] = acc;
  __syncthreads();

  if (t < 32) {
    float a = 0.f;
    for (int q = 0; q < 8; ++q) a += pacc[t][q];
    a = a * (1.0f / N_SEQ) + ((t < CH) ? bi[t] : bj[t - CH]);
    ab[t] = a;
    if (t < CH) a2[l * CH + t] = a;
  }
  __syncthreads();

  // T[l][cc][z] = sum_d b2[d] * Wo[(cc*16+d)*CZ + z]
  const int z   = t & (CZ - 1);
  const int chi = t >> 7;  // 0..1
  for (int q = 0; q < 8; ++q) {
    const int cc = chi * 8 + q;
    float accT = 0.f;
#pragma unroll
    for (int d = 0; d < CH; ++d)
      accT += ab[CH + d] * Wo[(cc * CH + d) * CZ + z];
    T[((size_t)l * CH + cc) * CZ + z] = accT;
  }
}

// ---------------- Kernel B: out[i,j,z] = sum_c a2[i,c]*T[j,c,z] + bo[z] ----
// grid (64 j-chunks, 8 i-chunks), block 256, no LDS, no barriers.
// Thread (z4 = t&31, js = t>>5) pins T[j0+js][*][z4] in 64 VGPRs, loops 64 i.
// a2[i,:] is block-uniform -> s_load. Wave stores 1 KB contiguous, NT.
__global__ __launch_bounds__(256) void kB_out(
    const float* __restrict__ a2, const float* __restrict__ T,
    const float* __restrict__ bo, float* __restrict__ out)
{
  const int t  = threadIdx.x;
  const int z4 = t & 31;   // which float4 of the 128 z's
  const int j  = blockIdx.x * 8 + (t >> 5);
  const int i0 = blockIdx.y * 64;

  float4 Treg[CH];
  {
    const float4* Tg = (const float4*)T + (size_t)j * (CH * 32) + z4;
#pragma unroll
    for (int c = 0; c < CH; ++c)
      Treg[c] = Tg[c * 32];
  }
  const float4 bov = ((const float4*)bo)[z4];

#define FMA4(av, tv) { acc.x += (av)*(tv).x; acc.y += (av)*(tv).y; \
                       acc.z += (av)*(tv).z; acc.w += (av)*(tv).w; }
#pragma unroll 2
  for (int ii = 0; ii < 64; ++ii) {
    const int i = i0 + ii;
    const float4* ar4 = (const float4*)(a2 + (size_t)i * CH);  // uniform -> s_load
    const float4 a0 = ar4[0], a1 = ar4[1], a2v = ar4[2], a3 = ar4[3];
    float4 acc = bov;
    FMA4(a0.x, Treg[0]);  FMA4(a0.y, Treg[1]);  FMA4(a0.z, Treg[2]);  FMA4(a0.w, Treg[3]);
    FMA4(a1.x, Treg[4]);  FMA4(a1.y, Treg[5]);  FMA4(a1.z, Treg[6]);  FMA4(a1.w, Treg[7]);
    FMA4(a2v.x, Treg[8]); FMA4(a2v.y, Treg[9]); FMA4(a2v.z, Treg[10]); FMA4(a2v.w, Treg[11]);
    FMA4(a3.x, Treg[12]); FMA4(a3.y, Treg[13]); FMA4(a3.z, Treg[14]); FMA4(a3.w, Treg[15]);
    floatx4* dst = (floatx4*)(out + ((size_t)i * L_DIM + j) * CZ) + z4;
    floatx4 accv = { acc.x, acc.y, acc.z, acc.w };
    __builtin_nontemporal_store(accv, dst);
  }
#undef FMA4
}

extern "C" void kernel_launch(void* const* d_in, const int* in_sizes, int n_in,
                              void* d_out, int out_size, void* d_ws, size_t ws_size,
                              hipStream_t stream) {
  const float* m     = (const float*)d_in[0];
  const float* gamma = (const float*)d_in[1];
  const float* beta  = (const float*)d_in[2];
  const float* Wi    = (const float*)d_in[3];
  const float* bi    = (const float*)d_in[4];
  const float* Wj    = (const float*)d_in[5];
  const float* bj    = (const float*)d_in[6];
  const float* Wo    = (const float*)d_in[7];
  const float* bo    = (const float*)d_in[8];
  float* out = (float*)d_out;

  char* ws = (char*)d_ws;
  float* a2 = (float*)ws;                                  // 32 KiB
  float* T  = (float*)(ws + (size_t)L_DIM * CH * 4);       // 4 MiB

  kA_ln_proj<<<dim3(L_DIM), 256, 0, stream>>>(m, gamma, beta,
                                              Wi, bi, Wj, bj, Wo, a2, T);
  kB_out<<<dim3(64, 8), 256, 0, stream>>>(a2, T, bo, out);
}